// Round 9
// baseline (425.987 us; speedup 1.0000x reference)
//
#include <hip/hip_runtime.h>
#include <hip/hip_bf16.h>
#include <hip/hip_fp16.h>

typedef _Float16 f16;
typedef _Float16 f16x8 __attribute__((ext_vector_type(8)));
typedef _Float16 f16x4 __attribute__((ext_vector_type(4)));
typedef __fp16 hf16x2 __attribute__((ext_vector_type(2)));   // cvt_pkrtz return type
typedef float f32x4 __attribute__((ext_vector_type(4)));
typedef float f32x16 __attribute__((ext_vector_type(16)));

#define NP   4096   // H*W
#define NB   8      // batch
#define CINC 256    // input channels
#define EMB  128
#define OUTC 256
#define BN_EPS 1e-5f

#define DSZ  ((size_t)NB * NP * EMB)      // 4194304 halves, per-dir tensor
#define TSZ  (2 * DSZ)                    // 8388608 halves

// async global->LDS, 16B per lane; LDS dest = uniform base + lane*16.
__device__ __forceinline__ void gload_lds16(const f16* g, f16* l) {
    __builtin_amdgcn_global_load_lds(
        (const __attribute__((address_space(1))) unsigned int*)g,
        (__attribute__((address_space(3))) unsigned int*)l, 16, 0, 0);
}

// =======================================================================
// Kernel 1: ALL 6 input projections in one launch. grid (32, 6, 8).
// V is written KEY-PERMUTED within each 16-key group (swap bit2<->bit3 of
// n&15) so attn's PV B-operand needs NO cross-half lane exchange.
// =======================================================================
__global__ __launch_bounds__(256) void proj_all_kernel(
    const float* __restrict__ Xrgb, const float* __restrict__ Xpl,
    const float* __restrict__ w0, const float* __restrict__ b0,
    const float* __restrict__ w1, const float* __restrict__ b1,
    const float* __restrict__ w2, const float* __restrict__ b2,
    const float* __restrict__ w3, const float* __restrict__ b3,
    const float* __restrict__ w4, const float* __restrict__ b4,
    const float* __restrict__ w5, const float* __restrict__ b5,
    f16* __restrict__ Qt, f16* __restrict__ Kt, f16* __restrict__ Vn)
{
    const int m0 = blockIdx.x * 128;
    const int p  = blockIdx.y;
    const int b  = blockIdx.z;
    const int s  = (p >= 3) ? 1 : 0;
    const int j  = p - s * 3;
    const int tid = threadIdx.x;
    const int w = tid >> 6, lane = tid & 63, quad = lane >> 4, lr = lane & 15;

    const float* X  = s ? Xpl : Xrgb;
    const float* W  = p == 0 ? w0 : p == 1 ? w1 : p == 2 ? w2
                    : p == 3 ? w3 : p == 4 ? w4 : w5;
    const float* Bi = p == 0 ? b0 : p == 1 ? b1 : p == 2 ? b2
                    : p == 3 ? b3 : p == 4 ? b4 : b5;

    __shared__ __align__(16) f16 smem[128 * 72 * 2];   // 36864 B
    f16* Al = smem;             // [128 n][72]
    f16* Bl = smem + 128 * 72;  // [128 d][72]

    f32x4 acc[2][8];
    #pragma unroll
    for (int mi = 0; mi < 2; ++mi)
        #pragma unroll
        for (int ni = 0; ni < 8; ++ni) acc[mi][ni] = (f32x4){0.f, 0.f, 0.f, 0.f};

    for (int kt = 0; kt < 4; ++kt) {
        const int kc0 = kt * 64;
        __syncthreads();
        for (int s2 = tid; s2 < 1024; s2 += 256) {
            const int n = s2 & 127, cg = s2 >> 7;
            f16 tmp[8];
            #pragma unroll
            for (int jj = 0; jj < 8; ++jj)
                tmp[jj] = (f16)X[((size_t)b * CINC + kc0 + cg * 8 + jj) * NP + m0 + n];
            *(f16x8*)&Al[n * 72 + cg * 8] = *(const f16x8*)tmp;
        }
        for (int s2 = tid; s2 < 1024; s2 += 256) {
            const int d = s2 >> 3, cg = s2 & 7;
            f16 tmp[8];
            #pragma unroll
            for (int jj = 0; jj < 8; ++jj)
                tmp[jj] = (f16)W[(size_t)d * CINC + kc0 + cg * 8 + jj];
            *(f16x8*)&Bl[d * 72 + cg * 8] = *(const f16x8*)tmp;
        }
        __syncthreads();
        #pragma unroll
        for (int ks = 0; ks < 2; ++ks) {
            f16x8 af[2], bfr[8];
            #pragma unroll
            for (int mi = 0; mi < 2; ++mi)
                af[mi] = *(const f16x8*)&Al[(w * 32 + mi * 16 + lr) * 72 + ks * 32 + quad * 8];
            #pragma unroll
            for (int ni = 0; ni < 8; ++ni)
                bfr[ni] = *(const f16x8*)&Bl[(ni * 16 + lr) * 72 + ks * 32 + quad * 8];
            #pragma unroll
            for (int mi = 0; mi < 2; ++mi)
                #pragma unroll
                for (int ni = 0; ni < 8; ++ni)
                    acc[mi][ni] = __builtin_amdgcn_mfma_f32_16x16x32_f16(
                        af[mi], bfr[ni], acc[mi][ni], 0, 0, 0);
        }
    }

    float bias[8];
    #pragma unroll
    for (int ni = 0; ni < 8; ++ni) bias[ni] = Bi[ni * 16 + lr];

    if (j < 2) {
        f16* out = (j == 0) ? (Qt + (size_t)s * DSZ) : (Kt + (size_t)(1 - s) * DSZ);
        #pragma unroll
        for (int mi = 0; mi < 2; ++mi)
            #pragma unroll
            for (int ni = 0; ni < 8; ++ni)
                #pragma unroll
                for (int r = 0; r < 4; ++r) {
                    const int n = m0 + w * 32 + mi * 16 + quad * 4 + r;
                    out[((size_t)b * NP + n) * EMB + ni * 16 + lr] =
                        (f16)(acc[mi][ni][r] + bias[ni]);
                }
    } else {
        f16* outV = Vn + (size_t)(1 - s) * DSZ;
        __syncthreads();
        f16* T = smem;                        // [128 d][136]
        // key-permute: swap(bit2,bit3) of key&15 (quad 1 <-> quad 2).
        const int quad_p = ((quad & 1) << 1) | (quad >> 1);
        #pragma unroll
        for (int mi = 0; mi < 2; ++mi)
            #pragma unroll
            for (int ni = 0; ni < 8; ++ni)
                #pragma unroll
                for (int r = 0; r < 4; ++r)
                    T[(ni * 16 + lr) * 136 + w * 32 + mi * 16 + quad_p * 4 + r] =
                        (f16)(acc[mi][ni][r] + bias[ni]);
        __syncthreads();
        for (int s2 = tid; s2 < 2048; s2 += 256) {
            const int d = s2 >> 4, n8 = (s2 & 15) * 8;
            *(f16x8*)&outV[((size_t)b * EMB + d) * NP + m0 + n8] =
                *(const f16x8*)&T[d * 136 + n8];
        }
    }
}

// =======================================================================
// Kernel 2: flash attention, 64 q/wave with IN-BLOCK key split.
//  - grid 512 = 32 n-blocks x 16 (dir,b); each block reads FULL K/V
//    (round-5's verified L2-resident pattern).
//  - Block = 128 q, 4 waves. Wave w: q-half (w>>1)*64, key-half (w&1).
//    Each kf/vf ds_read feeds 2 MFMAs (halves LDS read traffic vs r5).
//  - REGISTER LESSON (r3/r5/r7/r8 empirical): any min-waves>=2 constraint
//    ((256,2) or waves_per_eu(2,2)) makes the backend clamp to the
//    128-VGPR occupancy step and spill ~100 regs (scratch +40MB HBM, 2x
//    slow). (256,1) allocates by need (r3: 200 VGPR, no spill). At ~230
//    VGPR the HW still fits 2 waves/SIMD (460<=512) and LDS still fits
//    2 blocks/CU -> occupancy is preserved without the cap.
//  - K staged via global_load_lds with PRE-SWIZZLED global source (LDS
//    dest linear; XOR swizzle moved into per-lane global addr).
//  - V: register-staged into [128][40] padded rows (conflict-free b128).
//  - End: key-halves merged in-block via LDS (reuse K region):
//    O = rs0/(rs0+rs1)*Ohat0 + rs1/(rs0+rs1)*Ohat1  [verified r6/r7]
// =======================================================================
__global__ __launch_bounds__(256, 1) void attn_kernel(
    const f16* __restrict__ Qt, const f16* __restrict__ Kt,
    const f16* __restrict__ Vn, f16* __restrict__ combT)
{
    const int bid = blockIdx.x;
    const int g = bid & 15, dir = g >> 3, b = g & 7;
    const int n0 = (bid >> 4) * 128;
    const int tid = threadIdx.x;
    const int w = tid >> 6, lane = tid & 63;
    const int l31 = lane & 31, hi = lane >> 5;
    const int qsub = w >> 1;          // q-half within block
    const int kh   = w & 1;           // key-half handled by this wave

    const f16* __restrict__ Q = Qt + ((size_t)dir * NB + b) * NP * EMB;
    const f16* __restrict__ K = Kt + ((size_t)dir * NB + b) * NP * EMB;
    const f16* __restrict__ V = Vn + ((size_t)dir * NB + b) * (size_t)EMB * NP;

    __shared__ __align__(16) f16 Kl[2][2][32 * 128];  // [kh][buf][key][d] swz
    __shared__ __align__(16) f16 Vl[2][2][128 * 40];  // [kh][buf][d][pos] pad40

    const int qbase = n0 + qsub * 64;
    const int m00 = kh * 2048;

    // Q B-frags: B[k=d=hi*8+j][col=q=l31], scale*log2(e) folded in.
    f16x8 qf[2][8];
    #pragma unroll
    for (int q32 = 0; q32 < 2; ++q32)
        #pragma unroll
        for (int d16 = 0; d16 < 8; ++d16) {
            f16x8 q = *(const f16x8*)&Q[(size_t)(qbase + q32 * 32 + l31) * EMB + d16 * 16 + hi * 8];
            #pragma unroll
            for (int jj = 0; jj < 8; ++jj)
                q[jj] = q[jj] * (f16)0.12752749f;   // 128^-0.5 * log2(e)
            qf[q32][d16] = q;
        }

    f32x16 O[4][2];
    #pragma unroll
    for (int d32 = 0; d32 < 4; ++d32)
        #pragma unroll
        for (int q32 = 0; q32 < 2; ++q32) O[d32][q32] = (f32x16)(0.0f);
    float rs[2] = {0.f, 0.f};

    // staging lane decomposition
    const int krp = lane >> 4, kp = lane & 15;  // K: 4 rows x 16 chunks / call
    const int vrp = lane >> 2, vp = lane & 3;   // V: 16 rows x 4 chunks / load
    f16x8 stV[4];

    // K: async global->LDS, pre-swizzled source, linear dest.
    auto stage_loadK = [&](int t, int buf) {
        const int mk = m00 + t * 32;
        #pragma unroll
        for (int i = 0; i < 4; ++i) {
            const int r = qsub * 16 + i * 4 + krp;           // per-lane row
            const int c = kp ^ (r & 7);                      // swizzled chunk
            gload_lds16(&K[(size_t)(mk + r) * EMB + c * 8],
                        &Kl[kh][buf][(qsub * 16 + i * 4) * 128]);  // uniform base
        }
    };
    auto stage_loadV = [&](int t) {
        const int mk = m00 + t * 32;
        #pragma unroll
        for (int i = 0; i < 4; ++i) {
            const int rd = qsub * 64 + i * 16 + vrp;
            stV[i] = *(const f16x8*)&V[(size_t)rd * NP + mk + vp * 8];
        }
    };
    auto stage_writeV = [&](int buf) {
        #pragma unroll
        for (int i = 0; i < 4; ++i) {
            const int rd = qsub * 64 + i * 16 + vrp;
            *(f16x8*)&Vl[kh][buf][rd * 40 + vp * 8] = stV[i];
        }
    };

    stage_loadK(0, 0);
    stage_loadV(0);
    stage_writeV(0);
    int cur = 0;

    for (int t = 0; t < 64; ++t) {
        __syncthreads();                 // drains K gloads + V writes for cur
        if (t < 63) { stage_loadK(t + 1, cur ^ 1); stage_loadV(t + 1); }

        const f16* Kb = &Kl[kh][cur][0];
        const f16* Vb = &Vl[kh][cur][0];

        // ---- QK^T (swapped): S^T[key][q], 32 keys x 64 q ----
        f32x16 s0 = (f32x16)(0.0f), s1 = (f32x16)(0.0f);
        __builtin_amdgcn_s_setprio(1);
        #pragma unroll
        for (int d16 = 0; d16 < 8; ++d16) {
            const int c = (d16 * 2 + hi) ^ (l31 & 7);
            const f16x8 kf = *(const f16x8*)&Kb[l31 * 128 + c * 8];
            s0 = __builtin_amdgcn_mfma_f32_32x32x16_f16(kf, qf[0][d16], s0, 0, 0, 0);
            s1 = __builtin_amdgcn_mfma_f32_32x32x16_f16(kf, qf[1][d16], s1, 0, 0, 0);
        }
        __builtin_amdgcn_s_setprio(0);

        // ---- exp2 + rowsum + pack P (key-permuted V: no exchange) ----
        f16x8 pb[2][2];   // [key16-group][q32]
        #pragma unroll
        for (int q32 = 0; q32 < 2; ++q32) {
            const f32x16 s = q32 ? s1 : s0;
            float e[16];
            #pragma unroll
            for (int i = 0; i < 16; ++i) e[i] = __builtin_amdgcn_exp2f(s[i]);
            float sum = 0.f;
            #pragma unroll
            for (int i = 0; i < 16; ++i) sum += e[i];
            rs[q32] += sum;
            #pragma unroll
            for (int g2 = 0; g2 < 2; ++g2) {
                union { hf16x2 h[4]; f16x8 v; } pu;
                #pragma unroll
                for (int t2 = 0; t2 < 4; ++t2)
                    pu.h[t2] = __builtin_amdgcn_cvt_pkrtz(e[g2 * 8 + t2 * 2],
                                                          e[g2 * 8 + t2 * 2 + 1]);
                pb[g2][q32] = pu.v;
            }
        }

        // ---- PV: O^T[d][q] += V[d][pos] . P^T[pos][q] ----
        __builtin_amdgcn_s_setprio(1);
        #pragma unroll
        for (int g2 = 0; g2 < 2; ++g2) {
            #pragma unroll
            for (int d32 = 0; d32 < 4; ++d32) {
                const f16x8 vf = *(const f16x8*)&Vb[(d32 * 32 + l31) * 40 + (g2 * 2 + hi) * 8];
                O[d32][0] = __builtin_amdgcn_mfma_f32_32x32x16_f16(vf, pb[g2][0], O[d32][0], 0, 0, 0);
                O[d32][1] = __builtin_amdgcn_mfma_f32_32x32x16_f16(vf, pb[g2][1], O[d32][1], 0, 0, 0);
            }
        }
        __builtin_amdgcn_s_setprio(0);

        if (t < 63) stage_writeV(cur ^ 1);
        cur ^= 1;
    }

    // ---- merge key-halves within the block ----
    rs[0] += __shfl_xor(rs[0], 32);
    rs[1] += __shfl_xor(rs[1], 32);

    __syncthreads();                       // everyone done with K/V LDS
    f16*   Xch = (f16*)&Kl[0][0][0];       // [128 q][128 d] = 32 KB
    float* rsX = (float*)&Vl[0][0][0];     // [128 q]

    if (kh == 1) {
        // write locally-normalized partial + rowsum
        #pragma unroll
        for (int q32 = 0; q32 < 2; ++q32) {
            const float inv = 1.0f / rs[q32];
            const int ql = qsub * 64 + q32 * 32 + l31;
            #pragma unroll
            for (int d32 = 0; d32 < 4; ++d32)
                #pragma unroll
                for (int tq = 0; tq < 4; ++tq) {
                    f16 o4[4];
                    #pragma unroll
                    for (int jj = 0; jj < 4; ++jj)
                        o4[jj] = (f16)(O[d32][q32][tq * 4 + jj] * inv);
                    *(f16x4*)&Xch[ql * 128 + d32 * 32 + tq * 8 + hi * 4] = *(const f16x4*)o4;
                }
            if (hi == 0) rsX[ql] = rs[q32];
        }
    }
    __syncthreads();
    if (kh == 0) {
        #pragma unroll
        for (int q32 = 0; q32 < 2; ++q32) {
            const int ql = qsub * 64 + q32 * 32 + l31;
            const float rs1 = rsX[ql];
            const float wt = 1.0f / (rs[q32] + rs1);
            const float w1 = rs1 * wt;
            const int n = qbase + q32 * 32 + l31;
            #pragma unroll
            for (int d32 = 0; d32 < 4; ++d32)
                #pragma unroll
                for (int tq = 0; tq < 4; ++tq) {
                    const f16x4 oh = *(const f16x4*)&Xch[ql * 128 + d32 * 32 + tq * 8 + hi * 4];
                    f16 o4[4];
                    #pragma unroll
                    for (int jj = 0; jj < 4; ++jj)
                        o4[jj] = (f16)(O[d32][q32][tq * 4 + jj] * wt + (float)oh[jj] * w1);
                    *(f16x4*)&combT[((size_t)b * NP + n) * OUTC + dir * EMB + d32 * 32 + tq * 8 + hi * 4] =
                        *(const f16x4*)o4;
                }
        }
    }
}

// =======================================================================
// Kernel 3: output projection GEMM (MFMA) + BN + ReLU, fp32 out.
// =======================================================================
__global__ __launch_bounds__(256) void proj_out_kernel(
    const f16* __restrict__ combT, const float* __restrict__ Wp,
    const float* __restrict__ G, const float* __restrict__ Be,
    const float* __restrict__ Mu, const float* __restrict__ Va,
    float* __restrict__ out)
{
    const int m0 = blockIdx.x * 128;
    const int o0 = blockIdx.y * 128;
    const int b  = blockIdx.z;
    const int tid = threadIdx.x;
    const int w = tid >> 6, lane = tid & 63, quad = lane >> 4, lr = lane & 15;

    __shared__ __align__(16) f16 smem[128 * 72 * 2];
    f16* Al = smem;
    f16* Bl = smem + 128 * 72;

    f32x4 acc[2][8];
    #pragma unroll
    for (int mi = 0; mi < 2; ++mi)
        #pragma unroll
        for (int ni = 0; ni < 8; ++ni) acc[mi][ni] = (f32x4){0.f, 0.f, 0.f, 0.f};

    for (int kt = 0; kt < 4; ++kt) {
        const int kc0 = kt * 64;
        __syncthreads();
        #pragma unroll
        for (int i = 0; i < 4; ++i) {     // A tile: f16 straight copy
            const int s2 = i * 256 + tid;
            const int n = s2 >> 3, cg = s2 & 7;
            *(f16x8*)&Al[n * 72 + cg * 8] =
                *(const f16x8*)&combT[((size_t)b * NP + m0 + n) * OUTC + kc0 + cg * 8];
        }
        for (int s2 = tid; s2 < 1024; s2 += 256) {  // B tile: fp32 -> f16
            const int d = s2 >> 3, cg = s2 & 7;
            f16 tmp[8];
            #pragma unroll
            for (int jj = 0; jj < 8; ++jj)
                tmp[jj] = (f16)Wp[(size_t)(o0 + d) * OUTC + kc0 + cg * 8 + jj];
            *(f16x8*)&Bl[d * 72 + cg * 8] = *(const f16x8*)tmp;
        }
        __syncthreads();
        #pragma unroll
        for (int ks = 0; ks < 2; ++ks) {
            f16x8 af[2], bfr[8];
            #pragma unroll
            for (int mi = 0; mi < 2; ++mi)
                af[mi] = *(const f16x8*)&Al[(w * 32 + mi * 16 + lr) * 72 + ks * 32 + quad * 8];
            #pragma unroll
            for (int ni = 0; ni < 8; ++ni)
                bfr[ni] = *(const f16x8*)&Bl[(ni * 16 + lr) * 72 + ks * 32 + quad * 8];
            #pragma unroll
            for (int mi = 0; mi < 2; ++mi)
                #pragma unroll
                for (int ni = 0; ni < 8; ++ni)
                    acc[mi][ni] = __builtin_amdgcn_mfma_f32_16x16x32_f16(
                        af[mi], bfr[ni], acc[mi][ni], 0, 0, 0);
        }
    }

    __syncthreads();
    f16* T = smem;   // [128 o][136]
    #pragma unroll
    for (int ni = 0; ni < 8; ++ni) {
        const int o = o0 + ni * 16 + lr;
        const float iv = G[o] * rsqrtf(Va[o] + BN_EPS);
        const float sh = Be[o] - Mu[o] * iv;
        #pragma unroll
        for (int mi = 0; mi < 2; ++mi)
            #pragma unroll
            for (int r = 0; r < 4; ++r)
                T[(ni * 16 + lr) * 136 + w * 32 + mi * 16 + quad * 4 + r] =
                    (f16)fmaxf(acc[mi][ni][r] * iv + sh, 0.f);
    }
    __syncthreads();
    for (int s2 = tid; s2 < 2048; s2 += 256) {
        const int o = s2 >> 4, n8 = (s2 & 15) * 8;
        const f16x8 v = *(const f16x8*)&T[o * 136 + n8];
        const size_t off = ((size_t)b * OUTC + o0 + o) * NP + m0 + n8;
        #pragma unroll
        for (int k = 0; k < 8; ++k) out[off + k] = (float)v[k];
    }
}

extern "C" void kernel_launch(void* const* d_in, const int* in_sizes, int n_in,
                              void* d_out, int out_size, void* d_ws, size_t ws_size,
                              hipStream_t stream) {
    const float* f_rgb   = (const float*)d_in[0];
    const float* f_pl    = (const float*)d_in[1];
    const float* w_q_rgb = (const float*)d_in[2];  const float* b_q_rgb = (const float*)d_in[3];
    const float* w_k_pl  = (const float*)d_in[4];  const float* b_k_pl  = (const float*)d_in[5];
    const float* w_v_pl  = (const float*)d_in[6];  const float* b_v_pl  = (const float*)d_in[7];
    const float* w_q_pl  = (const float*)d_in[8];  const float* b_q_pl  = (const float*)d_in[9];
    const float* w_k_rgb = (const float*)d_in[10]; const float* b_k_rgb = (const float*)d_in[11];
    const float* w_v_rgb = (const float*)d_in[12]; const float* b_v_rgb = (const float*)d_in[13];
    const float* w_proj  = (const float*)d_in[14];
    const float* bn_g    = (const float*)d_in[15]; const float* bn_b = (const float*)d_in[16];
    const float* bn_m    = (const float*)d_in[17]; const float* bn_v = (const float*)d_in[18];

    // ws (halves): Qt | Kt | Vn | combT  = 4 * TSZ = 67.1 MB
    f16* Qt    = (f16*)d_ws;
    f16* Kt    = Qt + TSZ;
    f16* Vn    = Kt + TSZ;
    f16* combT = Vn + TSZ;

    proj_all_kernel<<<dim3(32, 6, 8), 256, 0, stream>>>(
        f_rgb, f_pl,
        w_q_rgb, b_q_rgb, w_k_rgb, b_k_rgb, w_v_rgb, b_v_rgb,
        w_q_pl,  b_q_pl,  w_k_pl,  b_k_pl,  w_v_pl,  b_v_pl,
        Qt, Kt, Vn);

    attn_kernel<<<512, 256, 0, stream>>>(Qt, Kt, Vn, combT);

    proj_out_kernel<<<dim3(32, 2, 8), 256, 0, stream>>>(
        combT, w_proj, bn_g, bn_b, bn_m, bn_v, (float*)d_out);
}

// Round 10
// 394.734 us; speedup vs baseline: 1.0792x; 1.0792x over previous
//
#include <hip/hip_runtime.h>
#include <hip/hip_bf16.h>
#include <hip/hip_fp16.h>

typedef _Float16 f16;
typedef _Float16 f16x8 __attribute__((ext_vector_type(8)));
typedef _Float16 f16x4 __attribute__((ext_vector_type(4)));
typedef __fp16 hf16x2 __attribute__((ext_vector_type(2)));   // cvt_pkrtz return type
typedef float f32x4 __attribute__((ext_vector_type(4)));
typedef float f32x16 __attribute__((ext_vector_type(16)));

#define NP   4096   // H*W
#define NB   8      // batch
#define CINC 256    // input channels
#define EMB  128
#define OUTC 256
#define BN_EPS 1e-5f

#define DSZ  ((size_t)NB * NP * EMB)      // 4194304 halves, per-dir tensor
#define TSZ  (2 * DSZ)                    // 8388608 halves

// async global->LDS, 16B per lane; LDS dest = uniform base + lane*16.
__device__ __forceinline__ void gload_lds16(const f16* g, f16* l) {
    __builtin_amdgcn_global_load_lds(
        (const __attribute__((address_space(1))) unsigned int*)g,
        (__attribute__((address_space(3))) unsigned int*)l, 16, 0, 0);
}

// =======================================================================
// Kernel 1: ALL 6 input projections in one launch. grid (32, 6, 8).
// V is written KEY-PERMUTED within each 16-key group (swap bit2<->bit3 of
// n&15) so attn's PV B-operand needs NO cross-half lane exchange.
// =======================================================================
__global__ __launch_bounds__(256) void proj_all_kernel(
    const float* __restrict__ Xrgb, const float* __restrict__ Xpl,
    const float* __restrict__ w0, const float* __restrict__ b0,
    const float* __restrict__ w1, const float* __restrict__ b1,
    const float* __restrict__ w2, const float* __restrict__ b2,
    const float* __restrict__ w3, const float* __restrict__ b3,
    const float* __restrict__ w4, const float* __restrict__ b4,
    const float* __restrict__ w5, const float* __restrict__ b5,
    f16* __restrict__ Qt, f16* __restrict__ Kt, f16* __restrict__ Vn)
{
    const int m0 = blockIdx.x * 128;
    const int p  = blockIdx.y;
    const int b  = blockIdx.z;
    const int s  = (p >= 3) ? 1 : 0;
    const int j  = p - s * 3;
    const int tid = threadIdx.x;
    const int w = tid >> 6, lane = tid & 63, quad = lane >> 4, lr = lane & 15;

    const float* X  = s ? Xpl : Xrgb;
    const float* W  = p == 0 ? w0 : p == 1 ? w1 : p == 2 ? w2
                    : p == 3 ? w3 : p == 4 ? w4 : w5;
    const float* Bi = p == 0 ? b0 : p == 1 ? b1 : p == 2 ? b2
                    : p == 3 ? b3 : p == 4 ? b4 : b5;

    __shared__ __align__(16) f16 smem[128 * 72 * 2];   // 36864 B
    f16* Al = smem;             // [128 n][72]
    f16* Bl = smem + 128 * 72;  // [128 d][72]

    f32x4 acc[2][8];
    #pragma unroll
    for (int mi = 0; mi < 2; ++mi)
        #pragma unroll
        for (int ni = 0; ni < 8; ++ni) acc[mi][ni] = (f32x4){0.f, 0.f, 0.f, 0.f};

    for (int kt = 0; kt < 4; ++kt) {
        const int kc0 = kt * 64;
        __syncthreads();
        for (int s2 = tid; s2 < 1024; s2 += 256) {
            const int n = s2 & 127, cg = s2 >> 7;
            f16 tmp[8];
            #pragma unroll
            for (int jj = 0; jj < 8; ++jj)
                tmp[jj] = (f16)X[((size_t)b * CINC + kc0 + cg * 8 + jj) * NP + m0 + n];
            *(f16x8*)&Al[n * 72 + cg * 8] = *(const f16x8*)tmp;
        }
        for (int s2 = tid; s2 < 1024; s2 += 256) {
            const int d = s2 >> 3, cg = s2 & 7;
            f16 tmp[8];
            #pragma unroll
            for (int jj = 0; jj < 8; ++jj)
                tmp[jj] = (f16)W[(size_t)d * CINC + kc0 + cg * 8 + jj];
            *(f16x8*)&Bl[d * 72 + cg * 8] = *(const f16x8*)tmp;
        }
        __syncthreads();
        #pragma unroll
        for (int ks = 0; ks < 2; ++ks) {
            f16x8 af[2], bfr[8];
            #pragma unroll
            for (int mi = 0; mi < 2; ++mi)
                af[mi] = *(const f16x8*)&Al[(w * 32 + mi * 16 + lr) * 72 + ks * 32 + quad * 8];
            #pragma unroll
            for (int ni = 0; ni < 8; ++ni)
                bfr[ni] = *(const f16x8*)&Bl[(ni * 16 + lr) * 72 + ks * 32 + quad * 8];
            #pragma unroll
            for (int mi = 0; mi < 2; ++mi)
                #pragma unroll
                for (int ni = 0; ni < 8; ++ni)
                    acc[mi][ni] = __builtin_amdgcn_mfma_f32_16x16x32_f16(
                        af[mi], bfr[ni], acc[mi][ni], 0, 0, 0);
        }
    }

    float bias[8];
    #pragma unroll
    for (int ni = 0; ni < 8; ++ni) bias[ni] = Bi[ni * 16 + lr];

    if (j < 2) {
        f16* out = (j == 0) ? (Qt + (size_t)s * DSZ) : (Kt + (size_t)(1 - s) * DSZ);
        #pragma unroll
        for (int mi = 0; mi < 2; ++mi)
            #pragma unroll
            for (int ni = 0; ni < 8; ++ni)
                #pragma unroll
                for (int r = 0; r < 4; ++r) {
                    const int n = m0 + w * 32 + mi * 16 + quad * 4 + r;
                    out[((size_t)b * NP + n) * EMB + ni * 16 + lr] =
                        (f16)(acc[mi][ni][r] + bias[ni]);
                }
    } else {
        f16* outV = Vn + (size_t)(1 - s) * DSZ;
        __syncthreads();
        f16* T = smem;                        // [128 d][136]
        // key-permute: swap(bit2,bit3) of key&15 (quad 1 <-> quad 2).
        const int quad_p = ((quad & 1) << 1) | (quad >> 1);
        #pragma unroll
        for (int mi = 0; mi < 2; ++mi)
            #pragma unroll
            for (int ni = 0; ni < 8; ++ni)
                #pragma unroll
                for (int r = 0; r < 4; ++r)
                    T[(ni * 16 + lr) * 136 + w * 32 + mi * 16 + quad_p * 4 + r] =
                        (f16)(acc[mi][ni][r] + bias[ni]);
        __syncthreads();
        for (int s2 = tid; s2 < 2048; s2 += 256) {
            const int d = s2 >> 4, n8 = (s2 & 15) * 8;
            *(f16x8*)&outV[((size_t)b * EMB + d) * NP + m0 + n8] =
                *(const f16x8*)&T[d * 136 + n8];
        }
    }
}

// =======================================================================
// Kernel 2: flash attention, 64 q/wave with IN-BLOCK key split.
//  - grid 512 = 32 n-blocks x 16 (dir,b); each block reads FULL K/V
//    (round-5's verified L2-resident pattern).
//  - Block = 128 q, 4 waves. Wave w: q-half (w>>1)*64, key-half (w&1).
//    Each kf/vf ds_read feeds 2 MFMAs (halves LDS read traffic vs r5).
//  - REGISTER MODEL (r5..r9 empirical): VGPR_Count = arch only; f32x16
//    accumulators sit in AGPRs (+128 here); occupancy=floor(512/total).
//    2 waves/SIMD needs arch<=128. waves_per_eu(2,2) pins arch=128; the
//    r7/r8 spill at that clamp came from stV[4] (16) + e[16] arrays (16)
//    -- both eliminated this round: V staged via global_load_lds, exp2
//    fused pairwise into cvt_pkrtz. Live peak ~120 <= 128 -> no spill.
//  - K: global_load_lds, pre-swizzled source c^=(row&7), LDS [32][128].
//  - V: global_load_lds, pre-swizzled source c^=((row>>1)&3), LDS
//    [128][32] linear rows. Read c=(g2*2+hi)^((l31>>1)&3): 64 lanes
//    spread over all 8 bank-quads -> conflict-free b128.
//  - End: key-halves merged in-block via LDS (reuse K region):
//    O = (O0_raw + O1_raw) / (rs0 + rs1)   [verified r6..r9]
// =======================================================================
__global__ __launch_bounds__(256) __attribute__((amdgpu_waves_per_eu(2, 2)))
void attn_kernel(
    const f16* __restrict__ Qt, const f16* __restrict__ Kt,
    const f16* __restrict__ Vn, f16* __restrict__ combT)
{
    const int bid = blockIdx.x;
    const int g = bid & 15, dir = g >> 3, b = g & 7;
    const int n0 = (bid >> 4) * 128;
    const int tid = threadIdx.x;
    const int w = tid >> 6, lane = tid & 63;
    const int l31 = lane & 31, hi = lane >> 5;
    const int qsub = w >> 1;          // q-half within block
    const int kh   = w & 1;           // key-half handled by this wave

    const f16* __restrict__ Q = Qt + ((size_t)dir * NB + b) * NP * EMB;
    const f16* __restrict__ K = Kt + ((size_t)dir * NB + b) * NP * EMB;
    const f16* __restrict__ V = Vn + ((size_t)dir * NB + b) * (size_t)EMB * NP;

    __shared__ __align__(16) f16 Kl[2][2][32 * 128];  // [kh][buf][key][d] swz(row&7)
    __shared__ __align__(16) f16 Vl[2][2][128 * 32];  // [kh][buf][d][pos] swz((row>>1)&3)

    const int qbase = n0 + qsub * 64;
    const int m00 = kh * 2048;

    // Q B-frags: B[k=d=hi*8+j][col=q=l31], scale*log2(e) folded in.
    f16x8 qf[2][8];
    #pragma unroll
    for (int q32 = 0; q32 < 2; ++q32)
        #pragma unroll
        for (int d16 = 0; d16 < 8; ++d16) {
            f16x8 q = *(const f16x8*)&Q[(size_t)(qbase + q32 * 32 + l31) * EMB + d16 * 16 + hi * 8];
            #pragma unroll
            for (int jj = 0; jj < 8; ++jj)
                q[jj] = q[jj] * (f16)0.12752749f;   // 128^-0.5 * log2(e)
            qf[q32][d16] = q;
        }

    f32x16 O[4][2];
    #pragma unroll
    for (int d32 = 0; d32 < 4; ++d32)
        #pragma unroll
        for (int q32 = 0; q32 < 2; ++q32) O[d32][q32] = (f32x16)(0.0f);
    float rs[2] = {0.f, 0.f};

    // staging lane decomposition (both tensors via global_load_lds)
    const int krp = lane >> 4, kp  = lane & 15;  // K: 4 rows x 16 chunks / gload
    const int vr4 = lane >> 2, vp4 = lane & 3;   // V: 16 rows x 4 chunks / gload

    auto stage_loadK = [&](int t, int buf) {
        const int mk = m00 + t * 32;
        #pragma unroll
        for (int i = 0; i < 4; ++i) {
            const int r = qsub * 16 + i * 4 + krp;           // per-lane row
            const int c = kp ^ (r & 7);                      // swizzled chunk
            gload_lds16(&K[(size_t)(mk + r) * EMB + c * 8],
                        &Kl[kh][buf][(qsub * 16 + i * 4) * 128]);  // uniform base
        }
    };
    auto stage_loadV = [&](int t, int buf) {
        const int mk = m00 + t * 32;
        #pragma unroll
        for (int i = 0; i < 4; ++i) {
            const int rd = qsub * 64 + i * 16 + vr4;         // per-lane d-row
            const int c = vp4 ^ ((rd >> 1) & 3);             // swizzled chunk
            gload_lds16(&V[(size_t)rd * NP + mk + c * 8],
                        &Vl[kh][buf][(qsub * 64 + i * 16) * 32]);  // uniform base
        }
    };

    stage_loadK(0, 0);
    stage_loadV(0, 0);
    int cur = 0;

    for (int t = 0; t < 64; ++t) {
        __syncthreads();                 // drains this wave's gloads for cur
        if (t < 63) { stage_loadK(t + 1, cur ^ 1); stage_loadV(t + 1, cur ^ 1); }

        const f16* Kb = &Kl[kh][cur][0];
        const f16* Vb = &Vl[kh][cur][0];

        // ---- QK^T (swapped): S^T[key][q], 32 keys x 64 q ----
        // kf transient: each read feeds the two q32 MFMAs immediately.
        f32x16 s0 = (f32x16)(0.0f), s1 = (f32x16)(0.0f);
        __builtin_amdgcn_s_setprio(1);
        #pragma unroll
        for (int d16 = 0; d16 < 8; ++d16) {
            const int c = (d16 * 2 + hi) ^ (l31 & 7);
            const f16x8 kf = *(const f16x8*)&Kb[l31 * 128 + c * 8];
            s0 = __builtin_amdgcn_mfma_f32_32x32x16_f16(kf, qf[0][d16], s0, 0, 0, 0);
            s1 = __builtin_amdgcn_mfma_f32_32x32x16_f16(kf, qf[1][d16], s1, 0, 0, 0);
        }
        __builtin_amdgcn_s_setprio(0);

        // ---- exp2 + rowsum + pack P, pairwise-inline (no e[] array) ----
        f16x8 pb[2][2];   // [key16-group][q32]
        #pragma unroll
        for (int q32 = 0; q32 < 2; ++q32) {
            const f32x16 s = q32 ? s1 : s0;
            float sum = 0.f;
            #pragma unroll
            for (int g2 = 0; g2 < 2; ++g2) {
                union { hf16x2 h[4]; f16x8 v; } pu;
                #pragma unroll
                for (int t2 = 0; t2 < 4; ++t2) {
                    const float e0 = __builtin_amdgcn_exp2f(s[g2 * 8 + t2 * 2]);
                    const float e1 = __builtin_amdgcn_exp2f(s[g2 * 8 + t2 * 2 + 1]);
                    sum += e0 + e1;
                    pu.h[t2] = __builtin_amdgcn_cvt_pkrtz(e0, e1);
                }
                pb[g2][q32] = pu.v;
            }
            rs[q32] += sum;
        }

        // ---- PV: O^T[d][q] += V[d][pos] . P^T[pos][q] ----
        __builtin_amdgcn_s_setprio(1);
        #pragma unroll
        for (int g2 = 0; g2 < 2; ++g2) {
            #pragma unroll
            for (int d32 = 0; d32 < 4; ++d32) {
                const int row = d32 * 32 + l31;
                const int c = (g2 * 2 + hi) ^ ((l31 >> 1) & 3);
                const f16x8 vf = *(const f16x8*)&Vb[row * 32 + c * 8];
                O[d32][0] = __builtin_amdgcn_mfma_f32_32x32x16_f16(vf, pb[g2][0], O[d32][0], 0, 0, 0);
                O[d32][1] = __builtin_amdgcn_mfma_f32_32x32x16_f16(vf, pb[g2][1], O[d32][1], 0, 0, 0);
            }
        }
        __builtin_amdgcn_s_setprio(0);

        cur ^= 1;
    }

    // ---- merge key-halves within the block ----
    rs[0] += __shfl_xor(rs[0], 32);
    rs[1] += __shfl_xor(rs[1], 32);

    __syncthreads();                       // everyone done with K/V LDS
    f16*   Xch = (f16*)&Kl[0][0][0];       // [128 q][128 d] = 32 KB
    float* rsX = (float*)&Vl[0][0][0];     // [128 q]

    if (kh == 1) {
        // write locally-normalized partial + rowsum
        #pragma unroll
        for (int q32 = 0; q32 < 2; ++q32) {
            const float inv = 1.0f / rs[q32];
            const int ql = qsub * 64 + q32 * 32 + l31;
            #pragma unroll
            for (int d32 = 0; d32 < 4; ++d32)
                #pragma unroll
                for (int tq = 0; tq < 4; ++tq) {
                    f16 o4[4];
                    #pragma unroll
                    for (int jj = 0; jj < 4; ++jj)
                        o4[jj] = (f16)(O[d32][q32][tq * 4 + jj] * inv);
                    *(f16x4*)&Xch[ql * 128 + d32 * 32 + tq * 8 + hi * 4] = *(const f16x4*)o4;
                }
            if (hi == 0) rsX[ql] = rs[q32];
        }
    }
    __syncthreads();
    if (kh == 0) {
        #pragma unroll
        for (int q32 = 0; q32 < 2; ++q32) {
            const int ql = qsub * 64 + q32 * 32 + l31;
            const float rs1 = rsX[ql];
            const float wt = 1.0f / (rs[q32] + rs1);
            const float w1 = rs1 * wt;
            const int n = qbase + q32 * 32 + l31;
            #pragma unroll
            for (int d32 = 0; d32 < 4; ++d32)
                #pragma unroll
                for (int tq = 0; tq < 4; ++tq) {
                    const f16x4 oh = *(const f16x4*)&Xch[ql * 128 + d32 * 32 + tq * 8 + hi * 4];
                    f16 o4[4];
                    #pragma unroll
                    for (int jj = 0; jj < 4; ++jj)
                        o4[jj] = (f16)(O[d32][q32][tq * 4 + jj] * wt + (float)oh[jj] * w1);
                    *(f16x4*)&combT[((size_t)b * NP + n) * OUTC + dir * EMB + d32 * 32 + tq * 8 + hi * 4] =
                        *(const f16x4*)o4;
                }
        }
    }
}

// =======================================================================
// Kernel 3: output projection GEMM (MFMA) + BN + ReLU, fp32 out.
// =======================================================================
__global__ __launch_bounds__(256) void proj_out_kernel(
    const f16* __restrict__ combT, const float* __restrict__ Wp,
    const float* __restrict__ G, const float* __restrict__ Be,
    const float* __restrict__ Mu, const float* __restrict__ Va,
    float* __restrict__ out)
{
    const int m0 = blockIdx.x * 128;
    const int o0 = blockIdx.y * 128;
    const int b  = blockIdx.z;
    const int tid = threadIdx.x;
    const int w = tid >> 6, lane = tid & 63, quad = lane >> 4, lr = lane & 15;

    __shared__ __align__(16) f16 smem[128 * 72 * 2];
    f16* Al = smem;
    f16* Bl = smem + 128 * 72;

    f32x4 acc[2][8];
    #pragma unroll
    for (int mi = 0; mi < 2; ++mi)
        #pragma unroll
        for (int ni = 0; ni < 8; ++ni) acc[mi][ni] = (f32x4){0.f, 0.f, 0.f, 0.f};

    for (int kt = 0; kt < 4; ++kt) {
        const int kc0 = kt * 64;
        __syncthreads();
        #pragma unroll
        for (int i = 0; i < 4; ++i) {     // A tile: f16 straight copy
            const int s2 = i * 256 + tid;
            const int n = s2 >> 3, cg = s2 & 7;
            *(f16x8*)&Al[n * 72 + cg * 8] =
                *(const f16x8*)&combT[((size_t)b * NP + m0 + n) * OUTC + kc0 + cg * 8];
        }
        for (int s2 = tid; s2 < 1024; s2 += 256) {  // B tile: fp32 -> f16
            const int d = s2 >> 3, cg = s2 & 7;
            f16 tmp[8];
            #pragma unroll
            for (int jj = 0; jj < 8; ++jj)
                tmp[jj] = (f16)Wp[(size_t)(o0 + d) * OUTC + kc0 + cg * 8 + jj];
            *(f16x8*)&Bl[d * 72 + cg * 8] = *(const f16x8*)tmp;
        }
        __syncthreads();
        #pragma unroll
        for (int ks = 0; ks < 2; ++ks) {
            f16x8 af[2], bfr[8];
            #pragma unroll
            for (int mi = 0; mi < 2; ++mi)
                af[mi] = *(const f16x8*)&Al[(w * 32 + mi * 16 + lr) * 72 + ks * 32 + quad * 8];
            #pragma unroll
            for (int ni = 0; ni < 8; ++ni)
                bfr[ni] = *(const f16x8*)&Bl[(ni * 16 + lr) * 72 + ks * 32 + quad * 8];
            #pragma unroll
            for (int mi = 0; mi < 2; ++mi)
                #pragma unroll
                for (int ni = 0; ni < 8; ++ni)
                    acc[mi][ni] = __builtin_amdgcn_mfma_f32_16x16x32_f16(
                        af[mi], bfr[ni], acc[mi][ni], 0, 0, 0);
        }
    }

    __syncthreads();
    f16* T = smem;   // [128 o][136]
    #pragma unroll
    for (int ni = 0; ni < 8; ++ni) {
        const int o = o0 + ni * 16 + lr;
        const float iv = G[o] * rsqrtf(Va[o] + BN_EPS);
        const float sh = Be[o] - Mu[o] * iv;
        #pragma unroll
        for (int mi = 0; mi < 2; ++mi)
            #pragma unroll
            for (int r = 0; r < 4; ++r)
                T[(ni * 16 + lr) * 136 + w * 32 + mi * 16 + quad * 4 + r] =
                    (f16)fmaxf(acc[mi][ni][r] * iv + sh, 0.f);
    }
    __syncthreads();
    for (int s2 = tid; s2 < 2048; s2 += 256) {
        const int o = s2 >> 4, n8 = (s2 & 15) * 8;
        const f16x8 v = *(const f16x8*)&T[o * 136 + n8];
        const size_t off = ((size_t)b * OUTC + o0 + o) * NP + m0 + n8;
        #pragma unroll
        for (int k = 0; k < 8; ++k) out[off + k] = (float)v[k];
    }
}

extern "C" void kernel_launch(void* const* d_in, const int* in_sizes, int n_in,
                              void* d_out, int out_size, void* d_ws, size_t ws_size,
                              hipStream_t stream) {
    const float* f_rgb   = (const float*)d_in[0];
    const float* f_pl    = (const float*)d_in[1];
    const float* w_q_rgb = (const float*)d_in[2];  const float* b_q_rgb = (const float*)d_in[3];
    const float* w_k_pl  = (const float*)d_in[4];  const float* b_k_pl  = (const float*)d_in[5];
    const float* w_v_pl  = (const float*)d_in[6];  const float* b_v_pl  = (const float*)d_in[7];
    const float* w_q_pl  = (const float*)d_in[8];  const float* b_q_pl  = (const float*)d_in[9];
    const float* w_k_rgb = (const float*)d_in[10]; const float* b_k_rgb = (const float*)d_in[11];
    const float* w_v_rgb = (const float*)d_in[12]; const float* b_v_rgb = (const float*)d_in[13];
    const float* w_proj  = (const float*)d_in[14];
    const float* bn_g    = (const float*)d_in[15]; const float* bn_b = (const float*)d_in[16];
    const float* bn_m    = (const float*)d_in[17]; const float* bn_v = (const float*)d_in[18];

    // ws (halves): Qt | Kt | Vn | combT  = 4 * TSZ = 67.1 MB
    f16* Qt    = (f16*)d_ws;
    f16* Kt    = Qt + TSZ;
    f16* Vn    = Kt + TSZ;
    f16* combT = Vn + TSZ;

    proj_all_kernel<<<dim3(32, 6, 8), 256, 0, stream>>>(
        f_rgb, f_pl,
        w_q_rgb, b_q_rgb, w_k_rgb, b_k_rgb, w_v_rgb, b_v_rgb,
        w_q_pl,  b_q_pl,  w_k_pl,  b_k_pl,  w_v_pl,  b_v_pl,
        Qt, Kt, Vn);

    attn_kernel<<<512, 256, 0, stream>>>(Qt, Kt, Vn, combT);

    proj_out_kernel<<<dim3(32, 2, 8), 256, 0, stream>>>(
        combT, w_proj, bn_g, bn_b, bn_m, bn_v, (float*)d_out);
}